// Round 8
// baseline (190.388 us; speedup 1.0000x reference)
//
#include <hip/hip_runtime.h>
#include <cstdint>
#include <cstddef>

#define NV 6
#define ND 256
#define NHEAD 8
#define NBEV 80
#define NQ 6400
#define NTOK 7441
#define MROWS (NV * NTOK)
#define MROWSP 44672              // 349 * 128, padded row count for featT
#define FEPS 1e-5f

// k_gemms grid: 349*2 value tiles + 50*3 off/aw tiles
#define VBLKS 698
#define GBLKS 848                 // % 8 == 0
#define GCHUNK (GBLKS / 8)

// k_prep flat ranges
#define PR_PROJ 150
#define PR_TR   2832              // 6 v * 118 m-tiles * 4 k-tiles
#define PR_BEV  800
#define PB0 PR_PROJ
#define PB1 (PB0 + PR_TR)         // 2982
#define PB2 (PB1 + PR_BEV)        // 3782
#define PB3 (PB2 + 256)           // vWt     -> 4038
#define PB4 (PB3 + 256)           // oaWt oW -> 4294
#define PB5 (PB4 + 128)           // oaWt aW -> 4422
#define PB6 (PB5 + 256)           // outWt   -> 4678
#define PBT (PB6 + 24)            // emb_proj-> 4702

typedef __attribute__((ext_vector_type(8))) short bfx8;
typedef __attribute__((ext_vector_type(4))) float fx4;

__device__ __forceinline__ unsigned short f2bf(float x) {
    uint32_t u = __builtin_bit_cast(uint32_t, x);
    u += 0x7FFFu + ((u >> 16) & 1u);
    return (unsigned short)(u >> 16);
}
__device__ __forceinline__ float lof(uint32_t u) {
    return __builtin_bit_cast(float, u << 16);
}
__device__ __forceinline__ float hif(uint32_t u) {
    return __builtin_bit_cast(float, u & 0xFFFF0000u);
}
__device__ __forceinline__ unsigned short f2h(float x) {
    return __builtin_bit_cast(unsigned short, (_Float16)x);
}
__device__ __forceinline__ float h2f(unsigned short h) {
    return (float)__builtin_bit_cast(_Float16, h);
}

// ---------------------------------------------------------------------------
// K_prep (flat 4702 x 256): proj | featT transpose | bevh | weight transposes
// | emb_proj.  featT[v*NTOK+tok][k] bf16 via LDS 64x64 tile transpose;
// stores vectorized to bfx8 (16B).
// ---------------------------------------------------------------------------
__global__ __launch_bounds__(256) void k_prep(
        const float* __restrict__ f0, const float* __restrict__ f1,
        const float* __restrict__ f2, const float* __restrict__ f3,
        const float* __restrict__ l2i, const float* __restrict__ bev,
        const float* __restrict__ ve, const float* __restrict__ le,
        const float* __restrict__ vW, const float* __restrict__ vB,
        const float* __restrict__ oW, const float* __restrict__ aW,
        const float* __restrict__ outW,
        float2* __restrict__ coords, int* __restrict__ mask,
        unsigned short* __restrict__ featT, unsigned short* __restrict__ bevh,
        unsigned short* __restrict__ vWt, unsigned short* __restrict__ oaWt,
        unsigned short* __restrict__ outWt, float* __restrict__ emb_proj) {
    int bid = blockIdx.x;
    int t = threadIdx.x;
    if (bid < PB0) {
        int idx = bid * 256 + t;
        int v = idx / NQ, q = idx - v * NQ;
        float xs = ((float)(q % NBEV) + 0.5f) / (float)NBEV;
        float ys = ((float)(q / NBEV) + 0.5f) / (float)NBEV;
        float x = xs * 96.0f - 48.0f;
        float y = ys * 96.0f - 48.0f;
        float z = x * 8.0f - 5.0f;  // faithful ref bug
        const float* M = l2i + v * 16;
        float ip0 = M[0] * x + M[1] * y + M[2] * z + M[3];
        float ip1 = M[4] * x + M[5] * y + M[6] * z + M[7];
        float ip2 = M[8] * x + M[9] * y + M[10] * z + M[11];
        float dz = fmaxf(ip2, FEPS);
        float xn = ip0 / dz / 800.0f;
        float yn = ip1 / dz / 448.0f;
        bool m = (ip2 > FEPS) && (xn > 0.0f) && (xn < 1.0f) && (yn > 0.0f) && (yn < 1.0f);
        coords[idx] = make_float2(xn, yn);
        mask[idx] = m ? 1 : 0;
    } else if (bid < PB1) {
        // ---- featT transpose: 64x64 tile via LDS, b128 stores ----
        __shared__ float T[64][65];
        int idx = bid - PB0;
        int v = idx / 472;
        int rem = idx - v * 472;
        int mt = rem >> 2, kt = rem & 3;
        int hw, p0, st;
        const float* base;
        if (mt < 88)       { base = f0; hw = 5600; st = 0;    p0 = mt * 64; }
        else if (mt < 110) { base = f1; hw = 1400; st = 5600; p0 = (mt - 88) * 64; }
        else if (mt < 116) { base = f2; hw = 350;  st = 7000; p0 = (mt - 110) * 64; }
        else               { base = f3; hw = 91;   st = 7350; p0 = (mt - 116) * 64; }
        int k0 = kt * 64;
        const float* src = base + (size_t)v * 256 * hw;
#pragma unroll
        for (int i = 0; i < 16; ++i) {
            int ii = t + i * 256;
            int kk = ii >> 6, mm = ii & 63;
            float val = (p0 + mm < hw) ? src[(size_t)(k0 + kk) * hw + p0 + mm] : 0.0f;
            T[kk][mm] = val;
        }
        __syncthreads();
        size_t row0 = (size_t)v * NTOK + st + p0;
        int slot = t & 7;
#pragma unroll
        for (int j = 0; j < 2; ++j) {
            int mm = (t >> 3) + j * 32;
            if (p0 + mm < hw) {
                bfx8 o;
#pragma unroll
                for (int jj = 0; jj < 8; ++jj)
                    o[jj] = (short)f2bf(T[slot * 8 + jj][mm]);
                *(bfx8*)&featT[(row0 + mm) * 256 + k0 + slot * 8] = o;
            }
        }
    } else if (bid < PB2) {
        size_t e = (size_t)(bid - PB1) * 2048 + t * 8;
        float4 a = *(const float4*)(bev + e);
        float4 b = *(const float4*)(bev + e + 4);
        bfx8 o;
        o[0] = (short)f2bf(a.x); o[1] = (short)f2bf(a.y);
        o[2] = (short)f2bf(a.z); o[3] = (short)f2bf(a.w);
        o[4] = (short)f2bf(b.x); o[5] = (short)f2bf(b.y);
        o[6] = (short)f2bf(b.z); o[7] = (short)f2bf(b.w);
        *(bfx8*)(bevh + e) = o;
    } else if (bid < PB3) {
        int e = (bid - PB2) * 256 + t;
        int k = e >> 8, n = e & 255;
        vWt[(size_t)n * 256 + k] = f2bf(vW[(size_t)k * 256 + n]);
    } else if (bid < PB4) {
        int e = (bid - PB3) * 256 + t;
        int k = e >> 8, n = e & 255;
        oaWt[(size_t)n * 256 + k] = f2bf(oW[(size_t)k * 256 + n]);
    } else if (bid < PB5) {
        int e = (bid - PB4) * 256 + t;
        int k = e >> 7, n = e & 127;
        oaWt[(size_t)(256 + n) * 256 + k] = f2bf(aW[(size_t)k * 128 + n]);
    } else if (bid < PB6) {
        int e = (bid - PB5) * 256 + t;
        int k = e >> 8, n = e & 255;
        outWt[(size_t)n * 256 + k] = f2bf(outW[(size_t)k * 256 + n]);
    } else {
        int blk = bid - PB6;  // v*4 + l
        int v = blk >> 2, l = blk & 3;
        float acc = vB[t];
        for (int d = 0; d < ND; ++d)
            acc += (ve[v * ND + d] + le[l * ND + d]) * vW[d * ND + t];
        emb_proj[blk * ND + t] = acc;
    }
}

// ---------------------------------------------------------------------------
// K_gemms (flat 848 blocks, XCD-chunk swizzled): unified bf16 MFMA GEMM,
// software-pipelined: BK=32, per-thread stage = 2 bfx8 (A) + 2 bfx8 (B)
// [FULL tile coverage: 256 thr x 16 shorts = 4096 = 128 rows x 32 k],
// next chunk prefetched into registers under the MFMA phase.
//   lb in [0,698): value = featT @ vWt^T + emb_proj -> bf16
//   lb in [698,848): [off|aw] = bevh @ oaWt^T + bias
// ---------------------------------------------------------------------------
__global__ __launch_bounds__(256) void k_gemms(
        const unsigned short* __restrict__ featT,
        const unsigned short* __restrict__ vWt, const float* __restrict__ emb_proj,
        unsigned short* __restrict__ value,
        const unsigned short* __restrict__ bevh,
        const unsigned short* __restrict__ oaWt,
        const float* __restrict__ oB, const float* __restrict__ aB,
        float* __restrict__ off, float* __restrict__ aw_pre) {
    __shared__ unsigned short As[128][40];
    __shared__ unsigned short Bs[128][40];
    int b = blockIdx.x;
    int lb = (b & 7) * GCHUNK + (b >> 3);
    int t = threadIdx.x;
    int lane = t & 63, w = t >> 6;
    int wm = w >> 1, wn = w & 1;
    int lr = lane & 15, lk = lane >> 4;

    bool isval = lb < VBLKS;
    int m0, c0;
    const unsigned short *ap, *bp;
    if (isval) {
        m0 = (lb >> 1) * 128; c0 = (lb & 1) * 128;
        ap = featT; bp = vWt;
    } else {
        int r6 = lb - VBLKS;               // 50 x 3
        m0 = (r6 / 3) * 128; c0 = (r6 % 3) * 128;
        ap = bevh; bp = oaWt;
    }
    int sr = t & 127, skh = (t >> 7) * 16;
    const unsigned short* arow = ap + (size_t)(m0 + sr) * 256 + skh;
    const unsigned short* brow = bp + (size_t)(c0 + sr) * 256 + skh;

    fx4 acc[4][4];
#pragma unroll
    for (int i = 0; i < 4; ++i)
#pragma unroll
        for (int j = 0; j < 4; ++j) acc[i][j] = (fx4)0.0f;

    bfx8 ar0 = *(const bfx8*)arow;
    bfx8 ar1 = *(const bfx8*)(arow + 8);
    bfx8 br0 = *(const bfx8*)brow;
    bfx8 br1 = *(const bfx8*)(brow + 8);
#pragma unroll
    for (int k0 = 0; k0 < 256; k0 += 32) {
        *(bfx8*)&As[sr][skh]     = ar0;
        *(bfx8*)&As[sr][skh + 8] = ar1;
        *(bfx8*)&Bs[sr][skh]     = br0;
        *(bfx8*)&Bs[sr][skh + 8] = br1;
        __syncthreads();
        if (k0 < 224) {
            ar0 = *(const bfx8*)(arow + k0 + 32);
            ar1 = *(const bfx8*)(arow + k0 + 40);
            br0 = *(const bfx8*)(brow + k0 + 32);
            br1 = *(const bfx8*)(brow + k0 + 40);
        }
        bfx8 bfv[4];
#pragma unroll
        for (int f = 0; f < 4; ++f)
            bfv[f] = *(bfx8*)&Bs[wn * 64 + f * 16 + lr][lk * 8];
#pragma unroll
        for (int fm = 0; fm < 4; ++fm) {
            bfx8 afv = *(bfx8*)&As[wm * 64 + fm * 16 + lr][lk * 8];
#pragma unroll
            for (int fn = 0; fn < 4; ++fn)
                acc[fm][fn] = __builtin_amdgcn_mfma_f32_16x16x32_bf16(
                    afv, bfv[fn], acc[fm][fn], 0, 0, 0);
        }
        __syncthreads();
    }

    if (isval) {
#pragma unroll
        for (int fm = 0; fm < 4; ++fm) {
#pragma unroll
            for (int r = 0; r < 4; ++r) {
                int m = m0 + wm * 64 + fm * 16 + lk * 4 + r;
                if (m >= MROWS) continue;
                int v = m / NTOK;
                int n = m - v * NTOK;
                int l = (n < 5600) ? 0 : (n < 7000) ? 1 : (n < 7350) ? 2 : 3;
                const float* ep = emb_proj + (size_t)(v * 4 + l) * ND;
#pragma unroll
                for (int fn = 0; fn < 4; ++fn) {
                    int col = c0 + wn * 64 + fn * 16 + lr;
                    value[(size_t)m * ND + col] = f2bf(acc[fm][fn][r] + ep[col]);
                }
            }
        }
    } else if (c0 < 256) {
#pragma unroll
        for (int fm = 0; fm < 4; ++fm) {
#pragma unroll
            for (int fn = 0; fn < 4; ++fn) {
                int col = c0 + wn * 64 + fn * 16 + lr;
                float bs = oB[col];
#pragma unroll
                for (int r = 0; r < 4; ++r) {
                    int m = m0 + wm * 64 + fm * 16 + lk * 4 + r;
                    off[(size_t)m * 256 + col] = acc[fm][fn][r] + bs;
                }
            }
        }
    } else {
#pragma unroll
        for (int fm = 0; fm < 4; ++fm) {
#pragma unroll
            for (int fn = 0; fn < 4; ++fn) {
                int col = wn * 64 + fn * 16 + lr;  // 0..127 within aw
                float bs = aB[col];
#pragma unroll
                for (int r = 0; r < 4; ++r) {
                    int m = m0 + wm * 64 + fm * 16 + lk * 4 + r;
                    aw_pre[(size_t)m * 128 + col] = acc[fm][fn][r] + bs;
                }
            }
        }
    }
}

// ---------------------------------------------------------------------------
// K_sample: 2 queries/block (thread = qq x channel-pair). Prologue: softmax +
// per-(q,v,combo) packed {4x token idx u16, 4x half weight} uint4 into LDS.
// Main loop per (v,combo): 1 x ds_read_b128 + 4 coalesced dword loads + 8 FMA.
// XCD-chunked block swizzle.
// ---------------------------------------------------------------------------
#define SQB 2
__global__ __launch_bounds__(256) void k_sample(
        const float2* __restrict__ coords, const int* __restrict__ mask,
        const float* __restrict__ off, const float* __restrict__ awlog,
        const unsigned short* __restrict__ value, float* __restrict__ slots) {
    __shared__ float aw_s[SQB][128];
    __shared__ uint4 lw_s[SQB][NV][128];
    __shared__ float2 cxy_s[SQB][NV];
    __shared__ int msk_s[SQB][NV];

    int b = blockIdx.x;                       // 3200, % 8 == 0
    int lb = (b & 7) * (NQ / SQB / 8) + (b >> 3);
    int q0 = lb * SQB;
    int t = threadIdx.x;
    if (t < SQB * NV) {
        int qq = t / NV, v = t - qq * NV;
        msk_s[qq][v] = mask[v * NQ + q0 + qq];
        cxy_s[qq][v] = coords[v * NQ + q0 + qq];
    }
    {
        int qq = t >> 7, c2 = t & 127;
        aw_s[qq][c2] = awlog[(size_t)(q0 + qq) * 128 + c2];
    }
    __syncthreads();
    if (t < SQB * NHEAD) {
        int qq = t >> 3, h = t & 7;
        float* p = &aw_s[qq][h * 16];
        float mx = p[0];
#pragma unroll
        for (int i = 1; i < 16; ++i) mx = fmaxf(mx, p[i]);
        float e[16];
        float s = 0.0f;
#pragma unroll
        for (int i = 0; i < 16; ++i) { e[i] = __expf(p[i] - mx); s += e[i]; }
        float inv = 1.0f / s;
#pragma unroll
        for (int i = 0; i < 16; ++i) p[i] = e[i] * inv;
    }
    __syncthreads();

    const int LW[4] = {100, 50, 25, 13};
    const int LH[4] = {56, 28, 14, 7};
    const int LST[4] = {0, 5600, 7000, 7350};
    for (int idx = t; idx < SQB * NV * 128; idx += 256) {
        int c2 = idx & 127;
        int rem = idx >> 7;
        int qq = rem / NV, v = rem - qq * NV;
        if (!msk_s[qq][v]) continue;
        int ll = (c2 >> 2) & 3;
        int iwl = LW[ll], ihl = LH[ll], st = LST[ll];
        float wl = (float)iwl, hl = (float)ihl;
        float2 o2 = *(const float2*)&off[(size_t)(q0 + qq) * 256 + 2 * c2];
        float2 cc = cxy_s[qq][v];
        float gx = cc.x * wl + o2.x - 0.5f;
        float gy = cc.y * hl + o2.y - 0.5f;
        float fxf = floorf(gx), fyf = floorf(gy);
        int x0 = (int)fxf, y0 = (int)fyf;
        float wx = gx - fxf, wy = gy - fyf;
        bool bx0 = (unsigned)x0 < (unsigned)iwl;
        bool bx1 = (unsigned)(x0 + 1) < (unsigned)iwl;
        bool by0 = (unsigned)y0 < (unsigned)ihl;
        bool by1 = (unsigned)(y0 + 1) < (unsigned)ihl;
        int cx0 = min(max(x0, 0), iwl - 1);
        int cx1 = min(max(x0 + 1, 0), iwl - 1);
        int cy0 = min(max(y0, 0), ihl - 1);
        int cy1 = min(max(y0 + 1, 0), ihl - 1);
        float wa = aw_s[qq][c2];
        int r0 = st + cy0 * iwl, r1 = st + cy1 * iwl;
        float w00 = (bx0 && by0) ? (1.0f - wx) * (1.0f - wy) * wa : 0.0f;
        float w01 = (bx1 && by0) ? wx * (1.0f - wy) * wa : 0.0f;
        float w10 = (bx0 && by1) ? (1.0f - wx) * wy * wa : 0.0f;
        float w11 = (bx1 && by1) ? wx * wy * wa : 0.0f;
        uint4 lw;
        lw.x = (uint32_t)(unsigned short)(r0 + cx0) | ((uint32_t)(unsigned short)(r0 + cx1) << 16);
        lw.y = (uint32_t)(unsigned short)(r1 + cx0) | ((uint32_t)(unsigned short)(r1 + cx1) << 16);
        lw.z = (uint32_t)f2h(w00) | ((uint32_t)f2h(w01) << 16);
        lw.w = (uint32_t)f2h(w10) | ((uint32_t)f2h(w11) << 16);
        lw_s[qq][v][c2] = lw;
    }
    __syncthreads();

    int qq = t >> 7, cp = t & 127;
    int hb = (cp >> 4) * 16;
    float acc0 = 0.0f, acc1 = 0.0f;
    int cnt = 0;
#pragma unroll
    for (int v = 0; v < NV; ++v) cnt += msk_s[qq][v];
    for (int v = 0; v < NV; ++v) {
        if (!msk_s[qq][v]) continue;
        const uint32_t* vb = (const uint32_t*)(value + (size_t)v * NTOK * 256) + cp;
#pragma unroll
        for (int ci = 0; ci < 16; ++ci) {
            uint4 lw = lw_s[qq][v][hb + ci];
            uint32_t u0 = vb[(size_t)(lw.x & 0xFFFF) * 128];
            uint32_t u1 = vb[(size_t)(lw.x >> 16) * 128];
            uint32_t u2 = vb[(size_t)(lw.y & 0xFFFF) * 128];
            uint32_t u3 = vb[(size_t)(lw.y >> 16) * 128];
            float w0 = h2f((unsigned short)(lw.z & 0xFFFF));
            float w1 = h2f((unsigned short)(lw.z >> 16));
            float w2 = h2f((unsigned short)(lw.w & 0xFFFF));
            float w3 = h2f((unsigned short)(lw.w >> 16));
            acc0 += w0 * lof(u0) + w1 * lof(u1) + w2 * lof(u2) + w3 * lof(u3);
            acc1 += w0 * hif(u0) + w1 * hif(u1) + w2 * hif(u2) + w3 * hif(u3);
        }
    }
    float invc = 1.0f / fmaxf((float)cnt, 1.0f);
    *(float2*)&slots[(size_t)(q0 + qq) * 256 + 2 * cp] = make_float2(acc0 * invc, acc1 * invc);
}

// ---------------------------------------------------------------------------
// K_out: out = slots @ outWt^T + outB + bev.  BM=64 x BN=128, BK=32,
// register-prefetch pipelined like k_gemms.
// ---------------------------------------------------------------------------
__global__ __launch_bounds__(256) void k_out(
        const float* __restrict__ A, const unsigned short* __restrict__ Bt,
        const float* __restrict__ bias, const float* __restrict__ addsrc,
        float* __restrict__ out) {
    __shared__ unsigned short As[64][40];
    __shared__ unsigned short Bs[128][40];
    int t = threadIdx.x;
    int m0 = blockIdx.x * 64, c0 = blockIdx.y * 128;
    int lane = t & 63, w = t >> 6;
    int wm = w >> 1, wn = w & 1;
    int lr = lane & 15, lk = lane >> 4;
    int mA = t & 63, kg = t >> 6;
    const float* ap = A + (size_t)(m0 + mA) * 256 + kg * 8;
    const unsigned short* bp = Bt + (size_t)(c0 + (t >> 1)) * 256 + (t & 1) * 16;
    fx4 acc[2][4];
#pragma unroll
    for (int i = 0; i < 2; ++i)
#pragma unroll
        for (int j = 0; j < 4; ++j) acc[i][j] = (fx4)0.0f;

    float4 va0 = *(const float4*)ap;
    float4 va1 = *(const float4*)(ap + 4);
    bfx8 brg = *(const bfx8*)bp;
    bfx8 brg2 = *(const bfx8*)(bp + 8);
#pragma unroll
    for (int k0 = 0; k0 < 256; k0 += 32) {
        bfx8 a8;
        a8[0] = (short)f2bf(va0.x); a8[1] = (short)f2bf(va0.y);
        a8[2] = (short)f2bf(va0.z); a8[3] = (short)f2bf(va0.w);
        a8[4] = (short)f2bf(va1.x); a8[5] = (short)f2bf(va1.y);
        a8[6] = (short)f2bf(va1.z); a8[7] = (short)f2bf(va1.w);
        *(bfx8*)&As[mA][kg * 8] = a8;
        *(bfx8*)&Bs[t >> 1][(t & 1) * 16] = brg;
        *(bfx8*)&Bs[t >> 1][(t & 1) * 16 + 8] = brg2;
        __syncthreads();
        if (k0 < 224) {
            va0 = *(const float4*)(ap + k0 + 32);
            va1 = *(const float4*)(ap + k0 + 36);
            brg = *(const bfx8*)(bp + k0 + 32);
            brg2 = *(const bfx8*)(bp + k0 + 40);
        }
        bfx8 bfv[4];
#pragma unroll
        for (int f = 0; f < 4; ++f)
            bfv[f] = *(bfx8*)&Bs[wn * 64 + f * 16 + lr][lk * 8];
#pragma unroll
        for (int fm = 0; fm < 2; ++fm) {
            bfx8 afv = *(bfx8*)&As[wm * 32 + fm * 16 + lr][lk * 8];
#pragma unroll
            for (int fn = 0; fn < 4; ++fn)
                acc[fm][fn] = __builtin_amdgcn_mfma_f32_16x16x32_bf16(
                    afv, bfv[fn], acc[fm][fn], 0, 0, 0);
        }
        __syncthreads();
    }
#pragma unroll
    for (int fm = 0; fm < 2; ++fm) {
#pragma unroll
        for (int fn = 0; fn < 4; ++fn) {
            int col = c0 + wn * 64 + fn * 16 + lr;
            float bs = bias[col];
#pragma unroll
            for (int r = 0; r < 4; ++r) {
                int m = m0 + wm * 32 + fm * 16 + lk * 4 + r;
                out[(size_t)m * 256 + col] =
                    acc[fm][fn][r] + bs + addsrc[(size_t)m * 256 + col];
            }
        }
    }
}

// ---------------------------------------------------------------------------
extern "C" void kernel_launch(void* const* d_in, const int* in_sizes, int n_in,
                              void* d_out, int out_size, void* d_ws, size_t ws_size,
                              hipStream_t stream) {
    const float* f0   = (const float*)d_in[0];
    const float* f1   = (const float*)d_in[1];
    const float* f2   = (const float*)d_in[2];
    const float* f3   = (const float*)d_in[3];
    const float* l2i  = (const float*)d_in[4];
    const float* bev  = (const float*)d_in[5];
    const float* le   = (const float*)d_in[6];
    const float* ve   = (const float*)d_in[7];
    const float* vW   = (const float*)d_in[8];
    const float* vB   = (const float*)d_in[9];
    const float* oW   = (const float*)d_in[10];
    const float* oB   = (const float*)d_in[11];
    const float* aW   = (const float*)d_in[12];
    const float* aB   = (const float*)d_in[13];
    const float* outW = (const float*)d_in[14];
    const float* outB = (const float*)d_in[15];
    float* out = (float*)d_out;

    char* ws = (char*)d_ws;
    size_t o = 0;
    auto alloc = [&](size_t bytes) {
        void* p = ws + o;
        o += (bytes + 255) & ~(size_t)255;
        return p;
    };
    float2* coords   = (float2*)alloc((size_t)NV * NQ * sizeof(float2));
    int*    mask     = (int*)alloc((size_t)NV * NQ * sizeof(int));
    float*  emb_proj = (float*)alloc((size_t)24 * ND * sizeof(float));
    float*  off      = (float*)alloc((size_t)NQ * 256 * sizeof(float));
    float*  aw_pre   = (float*)alloc((size_t)NQ * 128 * sizeof(float));
    float*  slots    = (float*)alloc((size_t)NQ * 256 * sizeof(float));
    unsigned short* value = (unsigned short*)alloc((size_t)MROWS * ND * sizeof(short));
    unsigned short* featT = (unsigned short*)alloc((size_t)MROWSP * ND * sizeof(short));
    unsigned short* bevh  = (unsigned short*)alloc((size_t)NQ * ND * sizeof(short));
    unsigned short* vWt   = (unsigned short*)alloc((size_t)256 * 256 * sizeof(short));
    unsigned short* oaWt  = (unsigned short*)alloc((size_t)384 * 256 * sizeof(short));
    unsigned short* outWt = (unsigned short*)alloc((size_t)256 * 256 * sizeof(short));

    k_prep<<<PBT, 256, 0, stream>>>(f0, f1, f2, f3, l2i, bev, ve, le, vW, vB,
                                    oW, aW, outW, coords, mask, featT, bevh,
                                    vWt, oaWt, outWt, emb_proj);
    k_gemms<<<GBLKS, 256, 0, stream>>>(featT, vWt, emb_proj, value,
                                       bevh, oaWt, oB, aB, off, aw_pre);
    k_sample<<<NQ / SQB, 256, 0, stream>>>(coords, mask, off, aw_pre, value, slots);
    dim3 gout(NQ / 64, 2);
    k_out<<<gout, 256, 0, stream>>>(slots, outWt, outB, bev, out);
}

// Round 9
// 181.178 us; speedup vs baseline: 1.0508x; 1.0508x over previous
//
#include <hip/hip_runtime.h>
#include <cstdint>
#include <cstddef>

#define NV 6
#define ND 256
#define NHEAD 8
#define NBEV 80
#define NQ 6400
#define NTOK 7441
#define MROWS (NV * NTOK)
#define MROWSP 44672              // 349 * 128, padded row count for featT
#define FEPS 1e-5f

// k_gemms grid: 349*2 value tiles + 50*3 off/aw tiles
#define VBLKS 698
#define GBLKS 848                 // % 8 == 0
#define GCHUNK (GBLKS / 8)

// k_prep flat ranges
#define PR_PROJ 150
#define PR_TR   2832              // 6 v * 118 m-tiles * 4 k-tiles
#define PR_BEV  800
#define PB0 PR_PROJ
#define PB1 (PB0 + PR_TR)         // 2982
#define PB2 (PB1 + PR_BEV)        // 3782
#define PB3 (PB2 + 256)           // vWt     -> 4038
#define PB4 (PB3 + 256)           // oaWt oW -> 4294
#define PB5 (PB4 + 128)           // oaWt aW -> 4422
#define PB6 (PB5 + 256)           // outWt   -> 4678
#define PBT (PB6 + 24)            // emb_proj-> 4702

typedef __attribute__((ext_vector_type(8))) short bfx8;
typedef __attribute__((ext_vector_type(4))) float fx4;

typedef __attribute__((address_space(3))) unsigned int lds_u32_t;
typedef __attribute__((address_space(1))) const unsigned int glb_u32_t;

__device__ __forceinline__ void gload16(const unsigned short* g, unsigned short* l) {
    __builtin_amdgcn_global_load_lds((glb_u32_t*)g, (lds_u32_t*)l, 16, 0, 0);
}

__device__ __forceinline__ unsigned short f2bf(float x) {
    uint32_t u = __builtin_bit_cast(uint32_t, x);
    u += 0x7FFFu + ((u >> 16) & 1u);
    return (unsigned short)(u >> 16);
}
__device__ __forceinline__ float lof(uint32_t u) {
    return __builtin_bit_cast(float, u << 16);
}
__device__ __forceinline__ float hif(uint32_t u) {
    return __builtin_bit_cast(float, u & 0xFFFF0000u);
}
__device__ __forceinline__ unsigned short f2h(float x) {
    return __builtin_bit_cast(unsigned short, (_Float16)x);
}
__device__ __forceinline__ float h2f(unsigned short h) {
    return (float)__builtin_bit_cast(_Float16, h);
}

// ---------------------------------------------------------------------------
// K_prep (flat 4702 x 256): proj | featT transpose | bevh | weight transposes
// | emb_proj.  (unchanged from R8)
// ---------------------------------------------------------------------------
__global__ __launch_bounds__(256) void k_prep(
        const float* __restrict__ f0, const float* __restrict__ f1,
        const float* __restrict__ f2, const float* __restrict__ f3,
        const float* __restrict__ l2i, const float* __restrict__ bev,
        const float* __restrict__ ve, const float* __restrict__ le,
        const float* __restrict__ vW, const float* __restrict__ vB,
        const float* __restrict__ oW, const float* __restrict__ aW,
        const float* __restrict__ outW,
        float2* __restrict__ coords, int* __restrict__ mask,
        unsigned short* __restrict__ featT, unsigned short* __restrict__ bevh,
        unsigned short* __restrict__ vWt, unsigned short* __restrict__ oaWt,
        unsigned short* __restrict__ outWt, float* __restrict__ emb_proj) {
    int bid = blockIdx.x;
    int t = threadIdx.x;
    if (bid < PB0) {
        int idx = bid * 256 + t;
        int v = idx / NQ, q = idx - v * NQ;
        float xs = ((float)(q % NBEV) + 0.5f) / (float)NBEV;
        float ys = ((float)(q / NBEV) + 0.5f) / (float)NBEV;
        float x = xs * 96.0f - 48.0f;
        float y = ys * 96.0f - 48.0f;
        float z = x * 8.0f - 5.0f;  // faithful ref bug
        const float* M = l2i + v * 16;
        float ip0 = M[0] * x + M[1] * y + M[2] * z + M[3];
        float ip1 = M[4] * x + M[5] * y + M[6] * z + M[7];
        float ip2 = M[8] * x + M[9] * y + M[10] * z + M[11];
        float dz = fmaxf(ip2, FEPS);
        float xn = ip0 / dz / 800.0f;
        float yn = ip1 / dz / 448.0f;
        bool m = (ip2 > FEPS) && (xn > 0.0f) && (xn < 1.0f) && (yn > 0.0f) && (yn < 1.0f);
        coords[idx] = make_float2(xn, yn);
        mask[idx] = m ? 1 : 0;
    } else if (bid < PB1) {
        // ---- featT transpose: 64x64 tile via LDS, b128 stores ----
        __shared__ float T[64][65];
        int idx = bid - PB0;
        int v = idx / 472;
        int rem = idx - v * 472;
        int mt = rem >> 2, kt = rem & 3;
        int hw, p0, st;
        const float* base;
        if (mt < 88)       { base = f0; hw = 5600; st = 0;    p0 = mt * 64; }
        else if (mt < 110) { base = f1; hw = 1400; st = 5600; p0 = (mt - 88) * 64; }
        else if (mt < 116) { base = f2; hw = 350;  st = 7000; p0 = (mt - 110) * 64; }
        else               { base = f3; hw = 91;   st = 7350; p0 = (mt - 116) * 64; }
        int k0 = kt * 64;
        const float* src = base + (size_t)v * 256 * hw;
#pragma unroll
        for (int i = 0; i < 16; ++i) {
            int ii = t + i * 256;
            int kk = ii >> 6, mm = ii & 63;
            float val = (p0 + mm < hw) ? src[(size_t)(k0 + kk) * hw + p0 + mm] : 0.0f;
            T[kk][mm] = val;
        }
        __syncthreads();
        size_t row0 = (size_t)v * NTOK + st + p0;
        int slot = t & 7;
#pragma unroll
        for (int j = 0; j < 2; ++j) {
            int mm = (t >> 3) + j * 32;
            if (p0 + mm < hw) {
                bfx8 o;
#pragma unroll
                for (int jj = 0; jj < 8; ++jj)
                    o[jj] = (short)f2bf(T[slot * 8 + jj][mm]);
                *(bfx8*)&featT[(row0 + mm) * 256 + k0 + slot * 8] = o;
            }
        }
    } else if (bid < PB2) {
        size_t e = (size_t)(bid - PB1) * 2048 + t * 8;
        float4 a = *(const float4*)(bev + e);
        float4 b = *(const float4*)(bev + e + 4);
        bfx8 o;
        o[0] = (short)f2bf(a.x); o[1] = (short)f2bf(a.y);
        o[2] = (short)f2bf(a.z); o[3] = (short)f2bf(a.w);
        o[4] = (short)f2bf(b.x); o[5] = (short)f2bf(b.y);
        o[6] = (short)f2bf(b.z); o[7] = (short)f2bf(b.w);
        *(bfx8*)(bevh + e) = o;
    } else if (bid < PB3) {
        int e = (bid - PB2) * 256 + t;
        int k = e >> 8, n = e & 255;
        vWt[(size_t)n * 256 + k] = f2bf(vW[(size_t)k * 256 + n]);
    } else if (bid < PB4) {
        int e = (bid - PB3) * 256 + t;
        int k = e >> 8, n = e & 255;
        oaWt[(size_t)n * 256 + k] = f2bf(oW[(size_t)k * 256 + n]);
    } else if (bid < PB5) {
        int e = (bid - PB4) * 256 + t;
        int k = e >> 7, n = e & 127;
        oaWt[(size_t)(256 + n) * 256 + k] = f2bf(aW[(size_t)k * 128 + n]);
    } else if (bid < PB6) {
        int e = (bid - PB5) * 256 + t;
        int k = e >> 8, n = e & 255;
        outWt[(size_t)n * 256 + k] = f2bf(outW[(size_t)k * 256 + n]);
    } else {
        int blk = bid - PB6;  // v*4 + l
        int v = blk >> 2, l = blk & 3;
        float acc = vB[t];
        for (int d = 0; d < ND; ++d)
            acc += (ve[v * ND + d] + le[l * ND + d]) * vW[d * ND + t];
        emb_proj[blk * ND + t] = acc;
    }
}

// ---------------------------------------------------------------------------
// K_gemms (flat 848 blocks, XCD-chunk swizzled): bf16 MFMA GEMM with
// global_load_lds (width=16) double-buffered staging, BK=64, one barrier
// per chunk. LDS linear [128][64]/operand; bank conflicts killed by XOR
// swizzle slot^=row&7 applied on the per-lane GLOBAL source address (HBM
// layout unswizzled; XOR permutes 16B slots within one 128B row) and the
// matching XOR on the ds_read byte offset.
//   lb in [0,698): value = featT @ vWt^T + emb_proj -> bf16
//   lb in [698,848): [off|aw] = bevh @ oaWt^T + bias
// ---------------------------------------------------------------------------
__global__ __launch_bounds__(256) void k_gemms(
        const unsigned short* __restrict__ featT,
        const unsigned short* __restrict__ vWt, const float* __restrict__ emb_proj,
        unsigned short* __restrict__ value,
        const unsigned short* __restrict__ bevh,
        const unsigned short* __restrict__ oaWt,
        const float* __restrict__ oB, const float* __restrict__ aB,
        float* __restrict__ off, float* __restrict__ aw_pre) {
    __shared__ unsigned short LDS[4 * 8192];   // [buf][op][128][64] = 64 KB
    int b = blockIdx.x;
    int lb = (b & 7) * GCHUNK + (b >> 3);
    int t = threadIdx.x;
    int lane = t & 63, w = t >> 6;
    int wm = w >> 1, wn = w & 1;
    int lr = lane & 15, lk = lane >> 4;

    bool isval = lb < VBLKS;
    int m0, c0;
    const unsigned short *ap, *bp;
    if (isval) {
        m0 = (lb >> 1) * 128; c0 = (lb & 1) * 128;
        ap = featT; bp = vWt;
    } else {
        int r6 = lb - VBLKS;               // 50 x 3
        m0 = (r6 / 3) * 128; c0 = (r6 % 3) * 128;
        ap = bevh; bp = oaWt;
    }

    // staging roles: wave w covers rows w*32..w*32+31 (4 calls x 8 rows)
    int rsub = lane >> 3;                  // row within 8-row group
    int kslx = (lane & 7) ^ rsub;          // XOR-swizzled true 16B slot
    const unsigned short* asrc = ap + (size_t)(m0 + w * 32 + rsub) * 256 + kslx * 8;
    const unsigned short* bsrc = bp + (size_t)(c0 + w * 32 + rsub) * 256 + kslx * 8;

    fx4 acc[4][4];
#pragma unroll
    for (int i = 0; i < 4; ++i)
#pragma unroll
        for (int j = 0; j < 4; ++j) acc[i][j] = (fx4)0.0f;

    auto STAGE = [&](int c, int buf) {
        const unsigned short* a = asrc + c * 64;
        const unsigned short* bb = bsrc + c * 64;
        unsigned short* la = &LDS[(buf * 2 + 0) * 8192 + w * 2048];
        unsigned short* lbp = &LDS[(buf * 2 + 1) * 8192 + w * 2048];
#pragma unroll
        for (int j = 0; j < 4; ++j) {
            gload16(a + j * 2048, la + j * 512);     // 8 rows x 128B per call
            gload16(bb + j * 2048, lbp + j * 512);
        }
    };
    auto COMPUTE = [&](int buf) {
        const char* Ab = (const char*)&LDS[(buf * 2 + 0) * 8192] + (wm * 64 + lr) * 128;
        const char* Bb = (const char*)&LDS[(buf * 2 + 1) * 8192] + (wn * 64 + lr) * 128;
#pragma unroll
        for (int s = 0; s < 2; ++s) {
            int xs = (((s * 4 + lk) ^ (lr & 7)) << 4);
            bfx8 bfv[4];
#pragma unroll
            for (int f = 0; f < 4; ++f)
                bfv[f] = *(const bfx8*)(Bb + f * 2048 + xs);
#pragma unroll
            for (int fm = 0; fm < 4; ++fm) {
                bfx8 afv = *(const bfx8*)(Ab + fm * 2048 + xs);
#pragma unroll
                for (int fn = 0; fn < 4; ++fn)
                    acc[fm][fn] = __builtin_amdgcn_mfma_f32_16x16x32_bf16(
                        afv, bfv[fn], acc[fm][fn], 0, 0, 0);
            }
        }
    };

    STAGE(0, 0);
#pragma unroll
    for (int c = 0; c < 4; ++c) {
        __syncthreads();                   // drains chunk-c DMA (vmcnt) + aligns
        if (c < 3) STAGE(c + 1, (c + 1) & 1);  // DMA flies under MFMA below
        COMPUTE(c & 1);
    }

    if (isval) {
#pragma unroll
        for (int fm = 0; fm < 4; ++fm) {
#pragma unroll
            for (int r = 0; r < 4; ++r) {
                int m = m0 + wm * 64 + fm * 16 + lk * 4 + r;
                if (m >= MROWS) continue;
                int v = m / NTOK;
                int n = m - v * NTOK;
                int l = (n < 5600) ? 0 : (n < 7000) ? 1 : (n < 7350) ? 2 : 3;
                const float* ep = emb_proj + (size_t)(v * 4 + l) * ND;
#pragma unroll
                for (int fn = 0; fn < 4; ++fn) {
                    int col = c0 + wn * 64 + fn * 16 + lr;
                    value[(size_t)m * ND + col] = f2bf(acc[fm][fn][r] + ep[col]);
                }
            }
        }
    } else if (c0 < 256) {
#pragma unroll
        for (int fm = 0; fm < 4; ++fm) {
#pragma unroll
            for (int fn = 0; fn < 4; ++fn) {
                int col = c0 + wn * 64 + fn * 16 + lr;
                float bs = oB[col];
#pragma unroll
                for (int r = 0; r < 4; ++r) {
                    int m = m0 + wm * 64 + fm * 16 + lk * 4 + r;
                    off[(size_t)m * 256 + col] = acc[fm][fn][r] + bs;
                }
            }
        }
    } else {
#pragma unroll
        for (int fm = 0; fm < 4; ++fm) {
#pragma unroll
            for (int fn = 0; fn < 4; ++fn) {
                int col = wn * 64 + fn * 16 + lr;  // 0..127 within aw
                float bs = aB[col];
#pragma unroll
                for (int r = 0; r < 4; ++r) {
                    int m = m0 + wm * 64 + fm * 16 + lk * 4 + r;
                    aw_pre[(size_t)m * 128 + col] = acc[fm][fn][r] + bs;
                }
            }
        }
    }
}

// ---------------------------------------------------------------------------
// K_sample: (unchanged from R8) 2 queries/block, packed uint4 LDS entries,
// XCD-chunked block swizzle.
// ---------------------------------------------------------------------------
#define SQB 2
__global__ __launch_bounds__(256) void k_sample(
        const float2* __restrict__ coords, const int* __restrict__ mask,
        const float* __restrict__ off, const float* __restrict__ awlog,
        const unsigned short* __restrict__ value, float* __restrict__ slots) {
    __shared__ float aw_s[SQB][128];
    __shared__ uint4 lw_s[SQB][NV][128];
    __shared__ float2 cxy_s[SQB][NV];
    __shared__ int msk_s[SQB][NV];

    int b = blockIdx.x;                       // 3200, % 8 == 0
    int lb = (b & 7) * (NQ / SQB / 8) + (b >> 3);
    int q0 = lb * SQB;
    int t = threadIdx.x;
    if (t < SQB * NV) {
        int qq = t / NV, v = t - qq * NV;
        msk_s[qq][v] = mask[v * NQ + q0 + qq];
        cxy_s[qq][v] = coords[v * NQ + q0 + qq];
    }
    {
        int qq = t >> 7, c2 = t & 127;
        aw_s[qq][c2] = awlog[(size_t)(q0 + qq) * 128 + c2];
    }
    __syncthreads();
    if (t < SQB * NHEAD) {
        int qq = t >> 3, h = t & 7;
        float* p = &aw_s[qq][h * 16];
        float mx = p[0];
#pragma unroll
        for (int i = 1; i < 16; ++i) mx = fmaxf(mx, p[i]);
        float e[16];
        float s = 0.0f;
#pragma unroll
        for (int i = 0; i < 16; ++i) { e[i] = __expf(p[i] - mx); s += e[i]; }
        float inv = 1.0f / s;
#pragma unroll
        for (int i = 0; i < 16; ++i) p[i] = e[i] * inv;
    }
    __syncthreads();

    const int LW[4] = {100, 50, 25, 13};
    const int LH[4] = {56, 28, 14, 7};
    const int LST[4] = {0, 5600, 7000, 7350};
    for (int idx = t; idx < SQB * NV * 128; idx += 256) {
        int c2 = idx & 127;
        int rem = idx >> 7;
        int qq = rem / NV, v = rem - qq * NV;
        if (!msk_s[qq][v]) continue;
        int ll = (c2 >> 2) & 3;
        int iwl = LW[ll], ihl = LH[ll], st = LST[ll];
        float wl = (float)iwl, hl = (float)ihl;
        float2 o2 = *(const float2*)&off[(size_t)(q0 + qq) * 256 + 2 * c2];
        float2 cc = cxy_s[qq][v];
        float gx = cc.x * wl + o2.x - 0.5f;
        float gy = cc.y * hl + o2.y - 0.5f;
        float fxf = floorf(gx), fyf = floorf(gy);
        int x0 = (int)fxf, y0 = (int)fyf;
        float wx = gx - fxf, wy = gy - fyf;
        bool bx0 = (unsigned)x0 < (unsigned)iwl;
        bool bx1 = (unsigned)(x0 + 1) < (unsigned)iwl;
        bool by0 = (unsigned)y0 < (unsigned)ihl;
        bool by1 = (unsigned)(y0 + 1) < (unsigned)ihl;
        int cx0 = min(max(x0, 0), iwl - 1);
        int cx1 = min(max(x0 + 1, 0), iwl - 1);
        int cy0 = min(max(y0, 0), ihl - 1);
        int cy1 = min(max(y0 + 1, 0), ihl - 1);
        float wa = aw_s[qq][c2];
        int r0 = st + cy0 * iwl, r1 = st + cy1 * iwl;
        float w00 = (bx0 && by0) ? (1.0f - wx) * (1.0f - wy) * wa : 0.0f;
        float w01 = (bx1 && by0) ? wx * (1.0f - wy) * wa : 0.0f;
        float w10 = (bx0 && by1) ? (1.0f - wx) * wy * wa : 0.0f;
        float w11 = (bx1 && by1) ? wx * wy * wa : 0.0f;
        uint4 lw;
        lw.x = (uint32_t)(unsigned short)(r0 + cx0) | ((uint32_t)(unsigned short)(r0 + cx1) << 16);
        lw.y = (uint32_t)(unsigned short)(r1 + cx0) | ((uint32_t)(unsigned short)(r1 + cx1) << 16);
        lw.z = (uint32_t)f2h(w00) | ((uint32_t)f2h(w01) << 16);
        lw.w = (uint32_t)f2h(w10) | ((uint32_t)f2h(w11) << 16);
        lw_s[qq][v][c2] = lw;
    }
    __syncthreads();

    int qq = t >> 7, cp = t & 127;
    int hb = (cp >> 4) * 16;
    float acc0 = 0.0f, acc1 = 0.0f;
    int cnt = 0;
#pragma unroll
    for (int v = 0; v < NV; ++v) cnt += msk_s[qq][v];
    for (int v = 0; v < NV; ++v) {
        if (!msk_s[qq][v]) continue;
        const uint32_t* vb = (const uint32_t*)(value + (size_t)v * NTOK * 256) + cp;
#pragma unroll
        for (int ci = 0; ci < 16; ++ci) {
            uint4 lw = lw_s[qq][v][hb + ci];
            uint32_t u0 = vb[(size_t)(lw.x & 0xFFFF) * 128];
            uint32_t u1 = vb[(size_t)(lw.x >> 16) * 128];
            uint32_t u2 = vb[(size_t)(lw.y & 0xFFFF) * 128];
            uint32_t u3 = vb[(size_t)(lw.y >> 16) * 128];
            float w0 = h2f((unsigned short)(lw.z & 0xFFFF));
            float w1 = h2f((unsigned short)(lw.z >> 16));
            float w2 = h2f((unsigned short)(lw.w & 0xFFFF));
            float w3 = h2f((unsigned short)(lw.w >> 16));
            acc0 += w0 * lof(u0) + w1 * lof(u1) + w2 * lof(u2) + w3 * lof(u3);
            acc1 += w0 * hif(u0) + w1 * hif(u1) + w2 * hif(u2) + w3 * hif(u3);
        }
    }
    float invc = 1.0f / fmaxf((float)cnt, 1.0f);
    *(float2*)&slots[(size_t)(q0 + qq) * 256 + 2 * cp] = make_float2(acc0 * invc, acc1 * invc);
}

// ---------------------------------------------------------------------------
// K_out: (unchanged from R8) out = slots @ outWt^T + outB + bev.
// ---------------------------------------------------------------------------
__global__ __launch_bounds__(256) void k_out(
        const float* __restrict__ A, const unsigned short* __restrict__ Bt,
        const float* __restrict__ bias, const float* __restrict__ addsrc,
        float* __restrict__ out) {
    __shared__ unsigned short As[64][40];
    __shared__ unsigned short Bs[128][40];
    int t = threadIdx.x;
    int m0 = blockIdx.x * 64, c0 = blockIdx.y * 128;
    int lane = t & 63, w = t >> 6;
    int wm = w >> 1, wn = w & 1;
    int lr = lane & 15, lk = lane >> 4;
    int mA = t & 63, kg = t >> 6;
    const float* ap = A + (size_t)(m0 + mA) * 256 + kg * 8;
    const unsigned short* bp = Bt + (size_t)(c0 + (t >> 1)) * 256 + (t & 1) * 16;
    fx4 acc[2][4];
#pragma unroll
    for (int i = 0; i < 2; ++i)
#pragma unroll
        for (int j = 0; j < 4; ++j) acc[i][j] = (fx4)0.0f;

    float4 va0 = *(const float4*)ap;
    float4 va1 = *(const float4*)(ap + 4);
    bfx8 brg = *(const bfx8*)bp;
    bfx8 brg2 = *(const bfx8*)(bp + 8);
#pragma unroll
    for (int k0 = 0; k0 < 256; k0 += 32) {
        bfx8 a8;
        a8[0] = (short)f2bf(va0.x); a8[1] = (short)f2bf(va0.y);
        a8[2] = (short)f2bf(va0.z); a8[3] = (short)f2bf(va0.w);
        a8[4] = (short)f2bf(va1.x); a8[5] = (short)f2bf(va1.y);
        a8[6] = (short)f2bf(va1.z); a8[7] = (short)f2bf(va1.w);
        *(bfx8*)&As[mA][kg * 8] = a8;
        *(bfx8*)&Bs[t >> 1][(t & 1) * 16] = brg;
        *(bfx8*)&Bs[t >> 1][(t & 1) * 16 + 8] = brg2;
        __syncthreads();
        if (k0 < 224) {
            va0 = *(const float4*)(ap + k0 + 32);
            va1 = *(const float4*)(ap + k0 + 36);
            brg = *(const bfx8*)(bp + k0 + 32);
            brg2 = *(const bfx8*)(bp + k0 + 40);
        }
        bfx8 bfv[4];
#pragma unroll
        for (int f = 0; f < 4; ++f)
            bfv[f] = *(bfx8*)&Bs[wn * 64 + f * 16 + lr][lk * 8];
#pragma unroll
        for (int fm = 0; fm < 2; ++fm) {
            bfx8 afv = *(bfx8*)&As[wm * 32 + fm * 16 + lr][lk * 8];
#pragma unroll
            for (int fn = 0; fn < 4; ++fn)
                acc[fm][fn] = __builtin_amdgcn_mfma_f32_16x16x32_bf16(
                    afv, bfv[fn], acc[fm][fn], 0, 0, 0);
        }
        __syncthreads();
    }
#pragma unroll
    for (int fm = 0; fm < 2; ++fm) {
#pragma unroll
        for (int fn = 0; fn < 4; ++fn) {
            int col = c0 + wn * 64 + fn * 16 + lr;
            float bs = bias[col];
#pragma unroll
            for (int r = 0; r < 4; ++r) {
                int m = m0 + wm * 32 + fm * 16 + lk * 4 + r;
                out[(size_t)m * 256 + col] =
                    acc[fm][fn][r] + bs + addsrc[(size_t)m * 256 + col];
            }
        }
    }
}

// ---------------------------------------------------------------------------
extern "C" void kernel_launch(void* const* d_in, const int* in_sizes, int n_in,
                              void* d_out, int out_size, void* d_ws, size_t ws_size,
                              hipStream_t stream) {
    const float* f0   = (const float*)d_in[0];
    const float* f1   = (const float*)d_in[1];
    const float* f2   = (const float*)d_in[2];
    const float* f3   = (const float*)d_in[3];
    const float* l2i  = (const float*)d_in[4];
    const float* bev  = (const float*)d_in[5];
    const float* le   = (const float*)d_in[6];
    const float* ve   = (const float*)d_in[7];
    const float* vW   = (const float*)d_in[8];
    const float* vB   = (const float*)d_in[9];
    const float* oW   = (const float*)d_in[10];
    const float* oB   = (const float*)d_in[11];
    const float* aW   = (const float*)d_in[12];
    const float* aB   = (const float*)d_in[13];
    const float* outW = (const float*)d_in[14];
    const float* outB = (const float*)d_in[15];
    float* out = (float*)d_out;

    char* ws = (char*)d_ws;
    size_t o = 0;
    auto alloc = [&](size_t bytes) {
        void* p = ws + o;
        o += (bytes + 255) & ~(size_t)255;
        return p;
    };
    float2* coords   = (float2*)alloc((size_t)NV * NQ * sizeof(float2));
    int*    mask     = (int*)alloc((size_t)NV * NQ * sizeof(int));
    float*  emb_proj = (float*)alloc((size_t)24 * ND * sizeof(float));
    float*  off      = (float*)alloc((size_t)NQ * 256 * sizeof(float));
    float*  aw_pre   = (float*)alloc((size_t)NQ * 128 * sizeof(float));
    float*  slots    = (float*)alloc((size_t)NQ * 256 * sizeof(float));
    unsigned short* value = (unsigned short*)alloc((size_t)MROWS * ND * sizeof(short));
    unsigned short* featT = (unsigned short*)alloc((size_t)MROWSP * ND * sizeof(short));
    unsigned short* bevh  = (unsigned short*)alloc((size_t)NQ * ND * sizeof(short));
    unsigned short* vWt   = (unsigned short*)alloc((size_t)256 * 256 * sizeof(short));
    unsigned short* oaWt  = (unsigned short*)alloc((size_t)384 * 256 * sizeof(short));
    unsigned short* outWt = (unsigned short*)alloc((size_t)256 * 256 * sizeof(short));

    k_prep<<<PBT, 256, 0, stream>>>(f0, f1, f2, f3, l2i, bev, ve, le, vW, vB,
                                    oW, aW, outW, coords, mask, featT, bevh,
                                    vWt, oaWt, outWt, emb_proj);
    k_gemms<<<GBLKS, 256, 0, stream>>>(featT, vWt, emb_proj, value,
                                       bevh, oaWt, oB, aB, off, aw_pre);
    k_sample<<<NQ / SQB, 256, 0, stream>>>(coords, mask, off, aw_pre, value, slots);
    dim3 gout(NQ / 64, 2);
    k_out<<<gout, 256, 0, stream>>>(slots, outWt, outB, bev, out);
}